// Round 2
// baseline (2218.625 us; speedup 1.0000x reference)
//
#include <hip/hip_runtime.h>
#include <hip/hip_bf16.h>

#define TLEN 2048
#define BSZ  2048
#define HIDD 128
#define RPW  16
#define STRH 136   // bf16 elem stride, rows 272B = 17*16B (b128-aligned)
#define STR3 68    // f32 stride for h3act

typedef float f32x4 __attribute__((ext_vector_type(4)));
typedef short bf16x8 __attribute__((ext_vector_type(8)));

__device__ __forceinline__ unsigned short f2b(float f) {
    __hip_bfloat16 h = __float2bfloat16(f);          // HW v_cvt, RNE
    union { __hip_bfloat16 h; unsigned short u; } v; v.h = h;
    return v.u;
}

// barrier that does NOT drain vmcnt: global prefetch/stores stay in flight
__device__ __forceinline__ void lgkm_barrier() {
    __builtin_amdgcn_sched_barrier(0);
    asm volatile("s_waitcnt lgkmcnt(0)" ::: "memory");
    __builtin_amdgcn_s_barrier();
    __builtin_amdgcn_sched_barrier(0);
}

// bank-conflict-free store/read index for [row][col] bf16 tiles:
// physical 8-elem chunk = (col>>3) ^ ((row>>2)&3); write side becomes exactly
// 2 lanes/bank (free), read side XORs by the lane's own row (legal, balanced).
__device__ __forceinline__ int hswz(int row, int col) {
    const int chunk = (col >> 3) ^ ((row >> 2) & 3);
    return row * STRH + (chunk << 3) + (col & 7);
}

__global__ __launch_bounds__(256, 1) void garch_scan_kernel(
    const float* __restrict__ returns, const float* __restrict__ log_rv,
    const float* __restrict__ p_omega, const float* __restrict__ p_beta,
    const float* __restrict__ p_tau1,  const float* __restrict__ p_tau2,
    const float* __restrict__ p_gamma, const float* __restrict__ p_xi,
    const float* __restrict__ p_phi,   const float* __restrict__ p_delta1,
    const float* __restrict__ p_delta2,const float* __restrict__ p_mu,
    const float* __restrict__ W1, const float* __restrict__ b1,
    const float* __restrict__ W2, const float* __restrict__ b2,
    const float* __restrict__ W3, const float* __restrict__ b3,
    const float* __restrict__ W4, const float* __restrict__ b4,
    float* __restrict__ out)
{
    const int tid  = threadIdx.x;
    const int w    = tid >> 6;     // wave 0..3
    const int lane = tid & 63;
    const int c16  = lane & 15;
    const int g    = lane >> 4;

    __shared__ __align__(16) unsigned short h1buf[RPW * STRH];
    __shared__ __align__(16) unsigned short h2buf[RPW * STRH];
    __shared__ __align__(16) float          h3act[RPW * STR3];

    const float omega = p_omega[0], beta = p_beta[0], tau1 = p_tau1[0],
                tau2 = p_tau2[0],  gma  = p_gamma[0], xi  = p_xi[0],
                phi  = p_phi[0],   d1   = p_delta1[0], d2 = p_delta2[0],
                mu   = p_mu[0],    b4s  = b4[0];

    const int grow = blockIdx.x * RPW + c16;       // this lane's batch row
    const size_t row_off = (size_t)grow * TLEN;

    // ---------------- prologue: weight fragments into registers ----------------
    // B-frag slot (g,e) of K-tile kk holds W[32*kk + 8*g + e][col]; A-frag reads
    // use the identical k-slotting, so contraction is k-order independent.
    bf16x8 w1f[2], w2f[4][2], w3f[4];
    float b1v[2], b2v[2], b3v;
    float w4r[16];
    #pragma unroll
    for (int ntl = 0; ntl < 2; ++ntl) {
        const int col = 32*w + 16*ntl + c16;
        b1v[ntl] = b1[col];
        b2v[ntl] = b2[col];
        bf16x8 a;
        #pragma unroll
        for (int e = 0; e < 8; ++e) {
            const int k = 8*g + e;
            ((unsigned short*)&a)[e] = (k < 5) ? f2b(W1[k*HIDD + col]) : (unsigned short)0;
        }
        w1f[ntl] = a;
        #pragma unroll
        for (int kk = 0; kk < 4; ++kk) {
            bf16x8 bfr;
            #pragma unroll
            for (int e = 0; e < 8; ++e) {
                const int k = 32*kk + 8*g + e;
                ((unsigned short*)&bfr)[e] = f2b(W2[k*HIDD + col]);
            }
            w2f[kk][ntl] = bfr;
        }
    }
    {
        const int col3 = 16*w + c16;
        b3v = b3[col3];
        #pragma unroll
        for (int kk = 0; kk < 4; ++kk) {
            bf16x8 bfr;
            #pragma unroll
            for (int e = 0; e < 8; ++e) {
                const int k = 32*kk + 8*g + e;
                ((unsigned short*)&bfr)[e] = f2b(W3[k*64 + col3]);
            }
            w3f[kk] = bfr;
        }
    }
    #pragma unroll
    for (int j = 0; j < 16; ++j) w4r[j] = W4[16*g + j];

    const int f_r = (c16 >> 2) & 3;   // read-side swizzle term (constant per lane)

    // ---------------- scan state ----------------
    float lh_c = 0.f;      // enh(t-1)
    float nb   = 0.f;      // omega + tau1*z + tau2*(z^2-1) + gamma*lx, from t-1
    float r_cur   = returns[row_off];
    float lrv_cur = log_rv[row_off];
    int ti = 0, di = 0;    // t % 78, (t/78) % 5

    for (int t = 0; t < TLEN; ++t) {
        // prefetch next inputs; stays in flight across lgkm-only barriers
        const int tn = (t + 1 < TLEN) ? t + 1 : t;
        const float r_nxt   = returns[row_off + tn];
        const float lrv_nxt = log_rv[row_off + tn];

        // off-chain per-step constants
        const unsigned short tod_b = f2b((float)ti * (1.f/77.f));
        const unsigned short dow_b = f2b((float)di * 0.25f);

        // ---- recurrence: critical chain is enh -> 1 fma -> lh ----
        float lh;
        if (t == 0) lh = lrv_cur;                       // log(exp(lrv)) == lrv
        else        lh = fmaf(beta, lh_c, nb);
        const float zv = (r_cur - mu) * __expf(-0.5f * lh);
        const float zz = fmaf(zv, zv, -1.f);
        const float lx = xi + phi*lh + d1*zv + d2*zz;
        const float uv = lrv_cur - lx;
        nb = omega + tau1*zv + tau2*zz + gma*lx;        // for t+1 (off-chain)
        const float pre = fmaf(0.01f, b4s, lh);         // lh + 0.01*b4 (off-chain)

        // ---- layer 1: feat (16x5 in K=32) @ W1, bias via C-operand ----
        bf16x8 a1 = {0,0,0,0,0,0,0,0};
        if (g == 0) {
            unsigned short* ap = (unsigned short*)&a1;
            ap[0]=f2b(lh); ap[1]=f2b(zv); ap[2]=f2b(uv); ap[3]=tod_b; ap[4]=dow_b;
        }
        #pragma unroll
        for (int ntl = 0; ntl < 2; ++ntl) {
            f32x4 c0 = {b1v[ntl], b1v[ntl], b1v[ntl], b1v[ntl]};
            f32x4 acc = __builtin_amdgcn_mfma_f32_16x16x32_bf16(a1, w1f[ntl], c0, 0,0,0);
            const int col = 32*w + 16*ntl + c16;
            #pragma unroll
            for (int i = 0; i < 4; ++i) {
                float x = acc[i];
                x = fmaxf(x, 0.1f*x);                     // LeakyReLU(0.1)
                h1buf[hswz(4*g + i, col)] = f2b(x);
            }
        }
        lgkm_barrier();

        // ---- layer 2: h1(16x128) @ W2, two independent K-chains ----
        bf16x8 a2[4];
        #pragma unroll
        for (int kk = 0; kk < 4; ++kk)
            a2[kk] = *(const bf16x8*)(h1buf + c16*STRH + ((((4*kk + g) ^ f_r) & 15) << 3));
        #pragma unroll
        for (int ntl = 0; ntl < 2; ++ntl) {
            f32x4 aA = {b2v[ntl], b2v[ntl], b2v[ntl], b2v[ntl]};
            f32x4 aB = {0.f, 0.f, 0.f, 0.f};
            aA = __builtin_amdgcn_mfma_f32_16x16x32_bf16(a2[0], w2f[0][ntl], aA, 0,0,0);
            aA = __builtin_amdgcn_mfma_f32_16x16x32_bf16(a2[1], w2f[1][ntl], aA, 0,0,0);
            aB = __builtin_amdgcn_mfma_f32_16x16x32_bf16(a2[2], w2f[2][ntl], aB, 0,0,0);
            aB = __builtin_amdgcn_mfma_f32_16x16x32_bf16(a2[3], w2f[3][ntl], aB, 0,0,0);
            const f32x4 acc = aA + aB;
            const int col = 32*w + 16*ntl + c16;
            #pragma unroll
            for (int i = 0; i < 4; ++i) {
                float x = acc[i];
                x = fmaxf(x, 0.1f*x);
                h2buf[hswz(4*g + i, col)] = f2b(x);
            }
        }
        lgkm_barrier();

        // ---- layer 3: h2(16x128) @ W3 -> cols [16w,16w+16) ----
        bf16x8 a3[4];
        #pragma unroll
        for (int kk = 0; kk < 4; ++kk)
            a3[kk] = *(const bf16x8*)(h2buf + c16*STRH + ((((4*kk + g) ^ f_r) & 15) << 3));
        {
            f32x4 aA = {b3v, b3v, b3v, b3v};
            f32x4 aB = {0.f, 0.f, 0.f, 0.f};
            aA = __builtin_amdgcn_mfma_f32_16x16x32_bf16(a3[0], w3f[0], aA, 0,0,0);
            aA = __builtin_amdgcn_mfma_f32_16x16x32_bf16(a3[1], w3f[1], aA, 0,0,0);
            aB = __builtin_amdgcn_mfma_f32_16x16x32_bf16(a3[2], w3f[2], aB, 0,0,0);
            aB = __builtin_amdgcn_mfma_f32_16x16x32_bf16(a3[3], w3f[3], aB, 0,0,0);
            const f32x4 acc = aA + aB;
            const int col3 = 16*w + c16;
            #pragma unroll
            for (int i = 0; i < 4; ++i) {
                float x = acc[i];
                x = fmaxf(x, 0.1f*x);
                h3act[(4*g + i)*STR3 + col3] = x;
            }
        }
        lgkm_barrier();

        // ---- layer 4: 64->1 dot; 4 indep FMA chains + tree, then 2 shuffles ----
        const float4* hp = (const float4*)(h3act + c16*STR3 + 16*g);
        const float4 q0 = hp[0], q1 = hp[1], q2 = hp[2], q3 = hp[3];
        float p0 = q0.x * w4r[0];
        p0 = fmaf(q0.y, w4r[1],  p0); p0 = fmaf(q0.z, w4r[2],  p0); p0 = fmaf(q0.w, w4r[3],  p0);
        float p1 = q1.x * w4r[4];
        p1 = fmaf(q1.y, w4r[5],  p1); p1 = fmaf(q1.z, w4r[6],  p1); p1 = fmaf(q1.w, w4r[7],  p1);
        float p2 = q2.x * w4r[8];
        p2 = fmaf(q2.y, w4r[9],  p2); p2 = fmaf(q2.z, w4r[10], p2); p2 = fmaf(q2.w, w4r[11], p2);
        float p3 = q3.x * w4r[12];
        p3 = fmaf(q3.y, w4r[13], p3); p3 = fmaf(q3.z, w4r[14], p3); p3 = fmaf(q3.w, w4r[15], p3);
        float p = (p0 + p1) + (p2 + p3);
        p += __shfl_xor(p, 16, 64);
        p += __shfl_xor(p, 32, 64);
        const float enh = fmaf(0.01f, p, pre);

        // ---- outputs: one stream per wave (every lane holds all 4 values) ----
        const float ov = (w == 0) ? enh : (w == 1) ? lx : (w == 2) ? zv : uv;
        if (g == 0)
            out[(size_t)w * (BSZ*(size_t)TLEN) + row_off + t] = ov;

        // ---- carry ----
        lh_c = enh;
        r_cur = r_nxt; lrv_cur = lrv_nxt;
        if (++ti == 78) { ti = 0; if (++di == 5) di = 0; }
    }
}

extern "C" void kernel_launch(void* const* d_in, const int* in_sizes, int n_in,
                              void* d_out, int out_size, void* d_ws, size_t ws_size,
                              hipStream_t stream) {
    (void)in_sizes; (void)n_in; (void)d_ws; (void)ws_size; (void)out_size;
    const float* returns = (const float*)d_in[0];
    const float* log_rv  = (const float*)d_in[1];
    const float* p_omega = (const float*)d_in[2];
    const float* p_beta  = (const float*)d_in[3];
    const float* p_tau1  = (const float*)d_in[4];
    const float* p_tau2  = (const float*)d_in[5];
    const float* p_gamma = (const float*)d_in[6];
    const float* p_xi    = (const float*)d_in[7];
    const float* p_phi   = (const float*)d_in[8];
    const float* p_d1    = (const float*)d_in[9];
    const float* p_d2    = (const float*)d_in[10];
    const float* p_mu    = (const float*)d_in[11];
    const float* W1 = (const float*)d_in[12];
    const float* b1 = (const float*)d_in[13];
    const float* W2 = (const float*)d_in[14];
    const float* b2 = (const float*)d_in[15];
    const float* W3 = (const float*)d_in[16];
    const float* b3 = (const float*)d_in[17];
    const float* W4 = (const float*)d_in[18];
    const float* b4 = (const float*)d_in[19];
    float* out = (float*)d_out;

    garch_scan_kernel<<<dim3(BSZ / RPW), dim3(256), 0, stream>>>(
        returns, log_rv, p_omega, p_beta, p_tau1, p_tau2, p_gamma, p_xi,
        p_phi, p_d1, p_d2, p_mu, W1, b1, W2, b2, W3, b3, W4, b4, out);
}